// Round 16
// baseline (19515.511 us; speedup 1.0000x reference)
//
#include <hip/hip_runtime.h>
#include <math.h>

typedef float f32x2 __attribute__((ext_vector_type(2)));
typedef float f32x4 __attribute__((ext_vector_type(4)));

#define LOG2E 1.4426950408889634f

__device__ __forceinline__ float rcp_fast(float x)  { return __builtin_amdgcn_rcpf(x); }
__device__ __forceinline__ float exp2_fast(float x) { return __builtin_amdgcn_exp2f(x); }
__device__ __forceinline__ float exp_fast(float x)  { return exp2_fast(x * LOG2E); }

// tanh(x) = 1 - 2/(e^{2x}+1). Saturates correctly at +-1.
__device__ __forceinline__ float tanh_fast(float x) {
    float e = exp2_fast(x * (2.0f * LOG2E));
    return 1.0f - 2.0f * rcp_fast(e + 1.0f);
}
// 0.5*(tanh(5x)+1) == sigmoid(10x)
__device__ __forceinline__ float step_fast(float x) {
    return rcp_fast(1.0f + exp2_fast(x * (-10.0f * LOG2E)));
}
__device__ __forceinline__ float sinh_fast(float x) {
    float e = exp2_fast(x * LOG2E);
    return 0.5f * e - 0.5f * rcp_fast(e);
}

__device__ __forceinline__ float readlane_f(float x, int l) {
    return __builtin_bit_cast(float,
        __builtin_amdgcn_readlane(__builtin_bit_cast(int, x), l));
}

// acc += a * b, packed f32x2, all-VGPR (legal VOP3P; R2/R3/R5-proven).
__device__ __forceinline__ void pk_fma(f32x2& acc, f32x2 a, f32x2 b) {
    asm("v_pk_fma_f32 %0, %1, %2, %0" : "+v"(acc) : "v"(a), "v"(b));
}

#define DPP_ADD(x, ctrl, rmask)                                                         \
    x += __builtin_bit_cast(float, __builtin_amdgcn_update_dpp(                         \
             0, __builtin_bit_cast(int, x), ctrl, rmask, 0xf, true))

// Full 64-lane sum via DPP; total lands in lane 63 -> readlane -> uniform.
__device__ __forceinline__ float wave_sum64(float x) {
    DPP_ADD(x, 0x111, 0xf);   // row_shr:1
    DPP_ADD(x, 0x112, 0xf);   // row_shr:2
    DPP_ADD(x, 0x114, 0xf);   // row_shr:4
    DPP_ADD(x, 0x118, 0xf);   // row_shr:8
    DPP_ADD(x, 0x142, 0xa);   // row_bcast:15
    DPP_ADD(x, 0x143, 0xc);   // row_bcast:31
    return readlane_f(x, 63);
}

// Barrier that waits ONLY on LDS ops (lgkmcnt), not global stores (vmcnt).
__device__ __forceinline__ void barrier_lgkm() {
    asm volatile("s_waitcnt lgkmcnt(0)" ::: "memory");
    __builtin_amdgcn_s_barrier();
    asm volatile("" ::: "memory");
}

// Same-wave LDS produce->consume ordering (DS pipe is in-order per wave);
// the asm fence stops compiler reordering, wave_barrier pins the schedule.
__device__ __forceinline__ void wave_fence() {
    asm volatile("" ::: "memory");
    __builtin_amdgcn_wave_barrier();
}

#define CHUNK 1024

// ---------------------------------------------------------------------------
// RK4 scan: 256 threads = 4 waves (R10/R15 structure).
// R16: layer 2 broadcast via wave-private LDS + packed FMA instead of
// readlane+fmac. h (32 values/wave) -> hbuf[w][ ] once (lanes<32, 1
// ds_write_b32, wave-private: no __syncthreads needed); layer 2 = 16
// broadcast ds_read_b64 + 32 all-VGPR v_pk_fma_f32 (W2 packed K-adjacent).
// Cuts ~66 VALU instr/wave/rhs (102 -> 36) and ALL readlane SGPR hazards;
// adds 17 DS ops on the (underused) DS pipe.
// ---------------------------------------------------------------------------
extern "C" __global__ void
__attribute__((amdgpu_flat_work_group_size(256, 256), amdgpu_waves_per_eu(1, 1)))
scan_kernel(const float* __restrict__ x,
            const float* __restrict__ precp,
            const float* __restrict__ temp,
            const float* __restrict__ lday,
            const float* __restrict__ W1, const float* __restrict__ b1,
            const float* __restrict__ W2, const float* __restrict__ b2,
            const float* __restrict__ W3, const float* __restrict__ b3,
            float* __restrict__ sol, int T)
{
    const int tid  = threadIdx.x;      // 0..255
    const int lane = tid & 63;
    const int w    = tid >> 6;         // wave 0..3 (owns K-rows 32w..32w+31)
    const int kcol = (w << 5) + (lane & 31);   // layer-1 column this lane computes

    __shared__ __align__(8) float hbuf[4][32];         // wave-private h values
    __shared__ __align__(8) f32x2 part2[2][4][64];     // [parity][wave][lane] = (col_a, col_b)
    __shared__ float pr_s[CHUNK + 1], tm_s[CHUNK + 1], ld_s[CHUNK + 1];

    // ---- layer-1 weights for column kcol ----
    float w1q[4];
#pragma unroll
    for (int i = 0; i < 4; ++i) w1q[i] = W1[i * 128 + kcol];
    float b1q = b1[kcol];

    // ---- layer-2 weights: rows [32w,32w+32), K-adjacent packed per column ----
    f32x2 w2pa[16], w2pb[16];          // (row 2m, row 2m+1) for col lane / lane+64
#pragma unroll
    for (int m = 0; m < 16; ++m) {
        const int row = (w << 5) + 2 * m;
        w2pa[m].x = W2[row * 128 + lane];
        w2pa[m].y = W2[(row + 1) * 128 + lane];
        w2pb[m].x = W2[row * 128 + lane + 64];
        w2pb[m].y = W2[(row + 1) * 128 + lane + 64];
    }
    f32x2 b2p;
    b2p.x = b2[lane];
    b2p.y = b2[lane + 64];

    // ---- layer-3 weights: columns lane and lane+64 ----
    float w3a[5], w3b[5];
#pragma unroll
    for (int c = 0; c < 5; ++c) {
        w3a[c] = W3[lane * 5 + c];
        w3b[c] = W3[(lane + 64) * 5 + c];
    }
    const float b30 = b3[0], b31 = b3[1], b32 = b3[2], b33 = b3[3], b34 = b3[4];

    float S0 = x[0], S1 = x[1];
    if (tid == 0) { sol[0] = S0; sol[1] = S1; }

    // rhs with hoisted apt (= b1 + pr*w12 + tm*w13) and sNT (= step(-tm))
    auto rhs = [&](int par, float z0, float z1, float apt, float sNT,
                   float ld, float& d0, float& d1) {
        // layer 1 critical path: 2 fma + tanh; publish to wave-private LDS
        const float a = fmaf(z1, w1q[1], fmaf(z0, w1q[0], apt));
        const float h = tanh_fast(a);
        if (lane < 32) hbuf[w][lane] = h;              // 1x ds_write_b32
        wave_fence();                                  // same-wave order (in-order DS pipe)

        // layer 2: 16 broadcast ds_read_b64 + 32 packed FMA (no readlanes)
        f32x2 acc_a0 = {0.f, 0.f}, acc_a1 = {0.f, 0.f};
        f32x2 acc_b0 = {0.f, 0.f}, acc_b1 = {0.f, 0.f};
        const f32x2* hv = reinterpret_cast<const f32x2*>(&hbuf[w][0]);
#pragma unroll
        for (int m = 0; m < 16; m += 2) {
            const f32x2 h0 = hv[m];
            const f32x2 h1 = hv[m + 1];
            pk_fma(acc_a0, h0, w2pa[m]);
            pk_fma(acc_b0, h0, w2pb[m]);
            pk_fma(acc_a1, h1, w2pa[m + 1]);
            pk_fma(acc_b1, h1, w2pb[m + 1]);
        }
        wave_fence();                                  // reads done before next stage's write
        const f32x2 sa2 = acc_a0 + acc_a1;
        const f32x2 sb2 = acc_b0 + acc_b1;
        f32x2 own;
        own.x = sa2.x + sa2.y;
        own.y = sb2.x + sb2.y;
        part2[par][w][lane] = own;                     // 1x ds_write_b64

        // independent transcendentals hide in the write->barrier window
        const float sS0 = step_fast(z0);
        const float sS1 = step_fast(z1);

        barrier_lgkm();                                // the ONE __syncthreads-class barrier

        // fan-in: 4x ds_read_b64 (broadcast, conflict-free) + packed adds
        const f32x2 q = (part2[par][0][lane] + part2[par][1][lane]) +
                        (part2[par][2][lane] + part2[par][3][lane]);
        const f32x2 sab = q + b2p;
        const float h2a = tanh_fast(sab.x);
        const float h2b = tanh_fast(sab.y);

        // layer 3: per-lane partials over 2 columns -> 5 wave sums (uniform)
        const float o0 = wave_sum64(fmaf(h2b, w3b[0], h2a * w3a[0])) + b30;
        const float o1 = wave_sum64(fmaf(h2b, w3b[1], h2a * w3a[1])) + b31;
        const float o2 = wave_sum64(fmaf(h2b, w3b[2], h2a * w3a[2])) + b32;
        const float o3 = wave_sum64(fmaf(h2b, w3b[3], h2a * w3a[3])) + b33;
        const float o4 = wave_sum64(fmaf(h2b, w3b[4], h2a * w3a[4])) + b34;

        // epilogue (uniform)
        const float melt = sS0 * sinh_fast(o2);        // relu(step)=step
        d0 = fmaxf(sinh_fast(o3) * sNT, 0.0f) - melt;
        d1 = fmaxf(sinh_fast(o4), 0.0f) + melt
             - sS1 * fmaf(ld, exp_fast(o0), exp_fast(o1));
    };

    // rolling register prefetch (B of step n == A of step n+1)
    float pB = precp[0], tB = temp[0], lB = lday[0];

    for (int cbase = 0; cbase < T - 1; cbase += CHUNK) {
        for (int i = tid; i <= CHUNK; i += 256) {
            int g = cbase + i;
            if (g < T) {
                pr_s[i] = precp[g];
                tm_s[i] = temp[g];
                ld_s[i] = lday[g];
            }
        }
        __syncthreads();

        const int len = min(T - 1 - cbase, CHUNK);
#pragma unroll 1
        for (int l = 0; l < len; ++l) {
            const float pA = pB, tA = tB, lA = lB;
            pB = pr_s[l + 1];
            tB = tm_s[l + 1];
            lB = ld_s[l + 1];
            const float pM = 0.5f * (pA + pB);
            const float tM = 0.5f * (tA + tB);
            const float lM = 0.5f * (lA + lB);

            // off-critical-path precomputes for the 3 (pr,tm) pairs
            const float aptA = fmaf(tA, w1q[3], fmaf(pA, w1q[2], b1q));
            const float aptM = fmaf(tM, w1q[3], fmaf(pM, w1q[2], b1q));
            const float aptB = fmaf(tB, w1q[3], fmaf(pB, w1q[2], b1q));
            const float sNTA = step_fast(-tA);
            const float sNTM = step_fast(-tM);
            const float sNTB = step_fast(-tB);

            float k10, k11, k20, k21, k30, k31, k40, k41;
            rhs(0, S0, S1, aptA, sNTA, lA, k10, k11);                          // h = 1
            rhs(1, fmaf(0.5f, k10, S0), fmaf(0.5f, k11, S1), aptM, sNTM, lM, k20, k21);
            rhs(0, fmaf(0.5f, k20, S0), fmaf(0.5f, k21, S1), aptM, sNTM, lM, k30, k31);

            // RK4 base combine hoisted parallel to stage 4's MLP
            const float c = 1.0f / 6.0f;
            const float base0 = fmaf(c, k10 + 2.0f * (k20 + k30), S0);
            const float base1 = fmaf(c, k11 + 2.0f * (k21 + k31), S1);

            rhs(1, k30 + S0, k31 + S1, aptB, sNTB, lB, k40, k41);

            S0 = fmaf(c, k40, base0);
            S1 = fmaf(c, k41, base1);
            if (tid == 0) {
                const int n = cbase + l;
                sol[2 * (n + 1)]     = S0;
                sol[2 * (n + 1) + 1] = S1;
            }
        }
        __syncthreads();   // protect series LDS re-stage vs stragglers
    }
}

// ---------------------------------------------------------------------------
// Output: y[t] = exp(mlp([sol0,sol1,x2,x3])[1]) — fully parallel, tiny.
// ---------------------------------------------------------------------------
extern "C" __global__ void __launch_bounds__(128)
out_kernel(const float* __restrict__ x,
           const float* __restrict__ sol,
           const float* __restrict__ W1, const float* __restrict__ b1,
           const float* __restrict__ W2, const float* __restrict__ b2,
           const float* __restrict__ W3, const float* __restrict__ b3,
           float* __restrict__ y, int T)
{
    const int j    = threadIdx.x;
    const int lane = j & 63;
    const int wv   = j >> 6;

    __shared__ __align__(16) float h1s[128];
    __shared__ float red[2];

    float w1c[4], w2c[128];
#pragma unroll
    for (int i = 0; i < 4; ++i)   w1c[i] = W1[i * 128 + j];
    const float b1j = b1[j];
#pragma unroll
    for (int i = 0; i < 128; ++i) w2c[i] = W2[i * 128 + j];
    const float b2j = b2[j];
    const float w31 = W3[j * 5 + 1];
    const float b31 = b3[1];

#pragma unroll 1
    for (int r = blockIdx.x; r < T; r += gridDim.x) {
        const float z0 = sol[2 * r], z1 = sol[2 * r + 1];
        const float z2 = x[4 * r + 2], z3 = x[4 * r + 3];
        float a = b1j;
        a = fmaf(z0, w1c[0], a);
        a = fmaf(z1, w1c[1], a);
        a = fmaf(z2, w1c[2], a);
        a = fmaf(z3, w1c[3], a);
        h1s[j] = tanh_fast(a);
        __syncthreads();
        float acc0 = 0.f, acc1 = 0.f, acc2 = 0.f, acc3 = 0.f;
#pragma unroll
        for (int i = 0; i < 128; i += 4) {
            const float4 hv = *reinterpret_cast<const float4*>(&h1s[i]);
            acc0 = fmaf(hv.x, w2c[i + 0], acc0);
            acc1 = fmaf(hv.y, w2c[i + 1], acc1);
            acc2 = fmaf(hv.z, w2c[i + 2], acc2);
            acc3 = fmaf(hv.w, w2c[i + 3], acc3);
        }
        const float h2 = tanh_fast(((acc0 + acc1) + (acc2 + acc3)) + b2j);
        float p = h2 * w31;
#pragma unroll
        for (int off = 32; off >= 1; off >>= 1)
            p += __shfl_xor(p, off);
        if (lane == 0) red[wv] = p;
        __syncthreads();
        if (j == 0) y[r] = exp_fast(red[0] + red[1] + b31);
        __syncthreads();
    }
}

// ---------------------------------------------------------------------------
extern "C" void kernel_launch(void* const* d_in, const int* in_sizes, int n_in,
                              void* d_out, int out_size, void* d_ws, size_t ws_size,
                              hipStream_t stream)
{
    const float* x      = (const float*)d_in[0];
    // d_in[1] = t_eval = arange(T) -> h == 1.0
    // d_in[2] = t_grid = arange(T)
    const float* precp  = (const float*)d_in[3];
    const float* temp   = (const float*)d_in[4];
    const float* lday   = (const float*)d_in[5];
    const float* W1     = (const float*)d_in[6];
    const float* b1     = (const float*)d_in[7];
    const float* W2     = (const float*)d_in[8];
    const float* b2     = (const float*)d_in[9];
    const float* W3     = (const float*)d_in[10];
    const float* b3     = (const float*)d_in[11];
    float*       y      = (float*)d_out;
    float*       sol    = (float*)d_ws;      // T*2 floats
    const int    T      = in_sizes[1];

    hipLaunchKernelGGL(scan_kernel, dim3(1), dim3(256), 0, stream,
                       x, precp, temp, lday,
                       W1, b1, W2, b2, W3, b3, sol, T);
    hipLaunchKernelGGL(out_kernel, dim3(256), dim3(128), 0, stream,
                       x, sol, W1, b1, W2, b2, W3, b3, y, T);
}

// Round 17
// 17034.122 us; speedup vs baseline: 1.1457x; 1.1457x over previous
//
#include <hip/hip_runtime.h>
#include <math.h>

typedef float f32x2 __attribute__((ext_vector_type(2)));
typedef float f32x4 __attribute__((ext_vector_type(4)));

#define LOG2E 1.4426950408889634f

__device__ __forceinline__ float rcp_fast(float x)  { return __builtin_amdgcn_rcpf(x); }
__device__ __forceinline__ float exp2_fast(float x) { return __builtin_amdgcn_exp2f(x); }
__device__ __forceinline__ float exp_fast(float x)  { return exp2_fast(x * LOG2E); }

// tanh(x) = 1 - 2/(e^{2x}+1). Saturates correctly at +-1.
__device__ __forceinline__ float tanh_fast(float x) {
    float e = exp2_fast(x * (2.0f * LOG2E));
    return 1.0f - 2.0f * rcp_fast(e + 1.0f);
}
// 0.5*(tanh(5x)+1) == sigmoid(10x)
__device__ __forceinline__ float step_fast(float x) {
    return rcp_fast(1.0f + exp2_fast(x * (-10.0f * LOG2E)));
}
__device__ __forceinline__ float sinh_fast(float x) {
    float e = exp2_fast(x * LOG2E);
    return 0.5f * e - 0.5f * rcp_fast(e);
}

__device__ __forceinline__ float readlane_f(float x, int l) {
    return __builtin_bit_cast(float,
        __builtin_amdgcn_readlane(__builtin_bit_cast(int, x), l));
}

// Broadcast lane k's value to all lanes: VGPR->VGPR on the DS pipe (no SGPR
// hazard, no LDS storage, issue overlaps VALU).
__device__ __forceinline__ float bperm_f(int k, float x) {
    return __builtin_bit_cast(float,
        __builtin_amdgcn_ds_bpermute(k << 2, __builtin_bit_cast(int, x)));
}

#define DPP_ADD(x, ctrl, rmask)                                                         \
    x += __builtin_bit_cast(float, __builtin_amdgcn_update_dpp(                         \
             0, __builtin_bit_cast(int, x), ctrl, rmask, 0xf, true))

// Full 64-lane sum via DPP; total lands in lane 63 -> readlane -> uniform.
__device__ __forceinline__ float wave_sum64(float x) {
    DPP_ADD(x, 0x111, 0xf);   // row_shr:1
    DPP_ADD(x, 0x112, 0xf);   // row_shr:2
    DPP_ADD(x, 0x114, 0xf);   // row_shr:4
    DPP_ADD(x, 0x118, 0xf);   // row_shr:8
    DPP_ADD(x, 0x142, 0xa);   // row_bcast:15
    DPP_ADD(x, 0x143, 0xc);   // row_bcast:31
    return readlane_f(x, 63);
}

// Barrier that waits ONLY on LDS ops (lgkmcnt), not global stores (vmcnt).
__device__ __forceinline__ void barrier_lgkm() {
    asm volatile("s_waitcnt lgkmcnt(0)" ::: "memory");
    __builtin_amdgcn_s_barrier();
    asm volatile("" ::: "memory");
}

#define CHUNK 1024

// ---------------------------------------------------------------------------
// RK4 scan: 256 threads = 4 waves (R15 structure, best measured: 17.04 ms).
// R17: layer-2 broadcast via ds_bpermute (DS pipe, VGPR->VGPR) instead of
// v_readlane (VALU, SGPR-hazard per fmac pair). 32 bpermute pipelined 4
// ahead + 64 all-VGPR fmac. R16's failure mode (LDS write->read turnaround)
// does not apply: bpermute is register-sourced.
// ---------------------------------------------------------------------------
extern "C" __global__ void
__attribute__((amdgpu_flat_work_group_size(256, 256), amdgpu_waves_per_eu(1, 1)))
scan_kernel(const float* __restrict__ x,
            const float* __restrict__ precp,
            const float* __restrict__ temp,
            const float* __restrict__ lday,
            const float* __restrict__ W1, const float* __restrict__ b1,
            const float* __restrict__ W2, const float* __restrict__ b2,
            const float* __restrict__ W3, const float* __restrict__ b3,
            float* __restrict__ sol, int T)
{
    const int tid  = threadIdx.x;      // 0..255
    const int lane = tid & 63;
    const int w    = tid >> 6;         // wave 0..3 (owns K-rows 32w..32w+31)
    const int kcol = (w << 5) + (lane & 31);   // layer-1 column this lane computes

    __shared__ __align__(8) f32x2 part2[2][4][64];     // [parity][wave][lane] = (col_a, col_b)
    __shared__ float pr_s[CHUNK + 1], tm_s[CHUNK + 1], ld_s[CHUNK + 1];

    // ---- layer-1 weights for column kcol ----
    float w1q[4];
#pragma unroll
    for (int i = 0; i < 4; ++i) w1q[i] = W1[i * 128 + kcol];
    float b1q = b1[kcol];

    // ---- layer-2 weights: rows [32w,32w+32) of columns lane and lane+64 ----
    float w2a[32], w2b[32];
#pragma unroll
    for (int k = 0; k < 32; ++k) {
        const int row = (w << 5) + k;
        w2a[k] = W2[row * 128 + lane];
        w2b[k] = W2[row * 128 + lane + 64];
    }
    f32x2 b2p;
    b2p.x = b2[lane];
    b2p.y = b2[lane + 64];

    // ---- layer-3 weights: columns lane and lane+64 ----
    float w3a[5], w3b[5];
#pragma unroll
    for (int c = 0; c < 5; ++c) {
        w3a[c] = W3[lane * 5 + c];
        w3b[c] = W3[(lane + 64) * 5 + c];
    }
    const float b30 = b3[0], b31 = b3[1], b32 = b3[2], b33 = b3[3], b34 = b3[4];

    float S0 = x[0], S1 = x[1];
    if (tid == 0) { sol[0] = S0; sol[1] = S1; }

    // rhs with hoisted apt (= b1 + pr*w12 + tm*w13) and sNT (= step(-tm))
    auto rhs = [&](int par, float z0, float z1, float apt, float sNT,
                   float ld, float& d0, float& d1) {
        // layer 1 critical path: 2 fma + tanh. Note: h lives in lanes 0-31's
        // column index (lane&31)+32w; lanes 32-63 compute the same columns, so
        // bpermute source lane k (k<32) holds h for K-row 32w+k. 
        const float a = fmaf(z1, w1q[1], fmaf(z0, w1q[0], apt));
        const float h = tanh_fast(a);

        // layer 2: ds_bpermute broadcast (DS pipe), pipelined 4 ahead; 8 accums
        float aa0 = 0.f, aa1 = 0.f, aa2 = 0.f, aa3 = 0.f;
        float ab0 = 0.f, ab1 = 0.f, ab2 = 0.f, ab3 = 0.f;
        float hk0 = bperm_f(0, h);
        float hk1 = bperm_f(1, h);
        float hk2 = bperm_f(2, h);
        float hk3 = bperm_f(3, h);
#pragma unroll
        for (int k = 0; k < 32; k += 4) {
            const float c0 = hk0, c1 = hk1, c2 = hk2, c3 = hk3;
            if (k + 4 < 32) {                  // prefetch next 4 broadcasts
                hk0 = bperm_f(k + 4, h);
                hk1 = bperm_f(k + 5, h);
                hk2 = bperm_f(k + 6, h);
                hk3 = bperm_f(k + 7, h);
            }
            aa0 = fmaf(c0, w2a[k],     aa0);
            ab0 = fmaf(c0, w2b[k],     ab0);
            aa1 = fmaf(c1, w2a[k + 1], aa1);
            ab1 = fmaf(c1, w2b[k + 1], ab1);
            aa2 = fmaf(c2, w2a[k + 2], aa2);
            ab2 = fmaf(c2, w2b[k + 2], ab2);
            aa3 = fmaf(c3, w2a[k + 3], aa3);
            ab3 = fmaf(c3, w2b[k + 3], ab3);
        }
        f32x2 own;
        own.x = (aa0 + aa1) + (aa2 + aa3);
        own.y = (ab0 + ab1) + (ab2 + ab3);
        part2[par][w][lane] = own;                         // 1x ds_write_b64

        // independent transcendentals hide in the write->barrier window
        const float sS0 = step_fast(z0);
        const float sS1 = step_fast(z1);

        barrier_lgkm();                                    // the ONE barrier

        // fan-in: 4x ds_read_b64 (broadcast, conflict-free) + packed adds
        const f32x2 q = (part2[par][0][lane] + part2[par][1][lane]) +
                        (part2[par][2][lane] + part2[par][3][lane]);
        const f32x2 sab = q + b2p;
        const float h2a = tanh_fast(sab.x);
        const float h2b = tanh_fast(sab.y);

        // layer 3: per-lane partials over 2 columns -> 5 wave sums (uniform)
        const float o0 = wave_sum64(fmaf(h2b, w3b[0], h2a * w3a[0])) + b30;
        const float o1 = wave_sum64(fmaf(h2b, w3b[1], h2a * w3a[1])) + b31;
        const float o2 = wave_sum64(fmaf(h2b, w3b[2], h2a * w3a[2])) + b32;
        const float o3 = wave_sum64(fmaf(h2b, w3b[3], h2a * w3a[3])) + b33;
        const float o4 = wave_sum64(fmaf(h2b, w3b[4], h2a * w3a[4])) + b34;

        // epilogue (uniform)
        const float melt = sS0 * sinh_fast(o2);            // relu(step)=step
        d0 = fmaxf(sinh_fast(o3) * sNT, 0.0f) - melt;
        d1 = fmaxf(sinh_fast(o4), 0.0f) + melt
             - sS1 * fmaf(ld, exp_fast(o0), exp_fast(o1));
    };

    // rolling register prefetch (B of step n == A of step n+1)
    float pB = precp[0], tB = temp[0], lB = lday[0];

    for (int cbase = 0; cbase < T - 1; cbase += CHUNK) {
        for (int i = tid; i <= CHUNK; i += 256) {
            int g = cbase + i;
            if (g < T) {
                pr_s[i] = precp[g];
                tm_s[i] = temp[g];
                ld_s[i] = lday[g];
            }
        }
        __syncthreads();

        const int len = min(T - 1 - cbase, CHUNK);
#pragma unroll 1
        for (int l = 0; l < len; ++l) {
            const float pA = pB, tA = tB, lA = lB;
            pB = pr_s[l + 1];
            tB = tm_s[l + 1];
            lB = ld_s[l + 1];
            const float pM = 0.5f * (pA + pB);
            const float tM = 0.5f * (tA + tB);
            const float lM = 0.5f * (lA + lB);

            // off-critical-path precomputes for the 3 (pr,tm) pairs
            const float aptA = fmaf(tA, w1q[3], fmaf(pA, w1q[2], b1q));
            const float aptM = fmaf(tM, w1q[3], fmaf(pM, w1q[2], b1q));
            const float aptB = fmaf(tB, w1q[3], fmaf(pB, w1q[2], b1q));
            const float sNTA = step_fast(-tA);
            const float sNTM = step_fast(-tM);
            const float sNTB = step_fast(-tB);

            float k10, k11, k20, k21, k30, k31, k40, k41;
            rhs(0, S0, S1, aptA, sNTA, lA, k10, k11);                          // h = 1
            rhs(1, fmaf(0.5f, k10, S0), fmaf(0.5f, k11, S1), aptM, sNTM, lM, k20, k21);
            rhs(0, fmaf(0.5f, k20, S0), fmaf(0.5f, k21, S1), aptM, sNTM, lM, k30, k31);

            // RK4 base combine hoisted parallel to stage 4's MLP
            const float c = 1.0f / 6.0f;
            const float base0 = fmaf(c, k10 + 2.0f * (k20 + k30), S0);
            const float base1 = fmaf(c, k11 + 2.0f * (k21 + k31), S1);

            rhs(1, k30 + S0, k31 + S1, aptB, sNTB, lB, k40, k41);

            S0 = fmaf(c, k40, base0);
            S1 = fmaf(c, k41, base1);
            if (tid == 0) {
                const int n = cbase + l;
                sol[2 * (n + 1)]     = S0;
                sol[2 * (n + 1) + 1] = S1;
            }
        }
        __syncthreads();   // protect series LDS re-stage vs stragglers
    }
}

// ---------------------------------------------------------------------------
// Output: y[t] = exp(mlp([sol0,sol1,x2,x3])[1]) — fully parallel, tiny.
// ---------------------------------------------------------------------------
extern "C" __global__ void __launch_bounds__(128)
out_kernel(const float* __restrict__ x,
           const float* __restrict__ sol,
           const float* __restrict__ W1, const float* __restrict__ b1,
           const float* __restrict__ W2, const float* __restrict__ b2,
           const float* __restrict__ W3, const float* __restrict__ b3,
           float* __restrict__ y, int T)
{
    const int j    = threadIdx.x;
    const int lane = j & 63;
    const int wv   = j >> 6;

    __shared__ __align__(16) float h1s[128];
    __shared__ float red[2];

    float w1c[4], w2c[128];
#pragma unroll
    for (int i = 0; i < 4; ++i)   w1c[i] = W1[i * 128 + j];
    const float b1j = b1[j];
#pragma unroll
    for (int i = 0; i < 128; ++i) w2c[i] = W2[i * 128 + j];
    const float b2j = b2[j];
    const float w31 = W3[j * 5 + 1];
    const float b31 = b3[1];

#pragma unroll 1
    for (int r = blockIdx.x; r < T; r += gridDim.x) {
        const float z0 = sol[2 * r], z1 = sol[2 * r + 1];
        const float z2 = x[4 * r + 2], z3 = x[4 * r + 3];
        float a = b1j;
        a = fmaf(z0, w1c[0], a);
        a = fmaf(z1, w1c[1], a);
        a = fmaf(z2, w1c[2], a);
        a = fmaf(z3, w1c[3], a);
        h1s[j] = tanh_fast(a);
        __syncthreads();
        float acc0 = 0.f, acc1 = 0.f, acc2 = 0.f, acc3 = 0.f;
#pragma unroll
        for (int i = 0; i < 128; i += 4) {
            const float4 hv = *reinterpret_cast<const float4*>(&h1s[i]);
            acc0 = fmaf(hv.x, w2c[i + 0], acc0);
            acc1 = fmaf(hv.y, w2c[i + 1], acc1);
            acc2 = fmaf(hv.z, w2c[i + 2], acc2);
            acc3 = fmaf(hv.w, w2c[i + 3], acc3);
        }
        const float h2 = tanh_fast(((acc0 + acc1) + (acc2 + acc3)) + b2j);
        float p = h2 * w31;
#pragma unroll
        for (int off = 32; off >= 1; off >>= 1)
            p += __shfl_xor(p, off);
        if (lane == 0) red[wv] = p;
        __syncthreads();
        if (j == 0) y[r] = exp_fast(red[0] + red[1] + b31);
        __syncthreads();
    }
}

// ---------------------------------------------------------------------------
extern "C" void kernel_launch(void* const* d_in, const int* in_sizes, int n_in,
                              void* d_out, int out_size, void* d_ws, size_t ws_size,
                              hipStream_t stream)
{
    const float* x      = (const float*)d_in[0];
    // d_in[1] = t_eval = arange(T) -> h == 1.0
    // d_in[2] = t_grid = arange(T)
    const float* precp  = (const float*)d_in[3];
    const float* temp   = (const float*)d_in[4];
    const float* lday   = (const float*)d_in[5];
    const float* W1     = (const float*)d_in[6];
    const float* b1     = (const float*)d_in[7];
    const float* W2     = (const float*)d_in[8];
    const float* b2     = (const float*)d_in[9];
    const float* W3     = (const float*)d_in[10];
    const float* b3     = (const float*)d_in[11];
    float*       y      = (float*)d_out;
    float*       sol    = (float*)d_ws;      // T*2 floats
    const int    T      = in_sizes[1];

    hipLaunchKernelGGL(scan_kernel, dim3(1), dim3(256), 0, stream,
                       x, precp, temp, lday,
                       W1, b1, W2, b2, W3, b3, sol, T);
    hipLaunchKernelGGL(out_kernel, dim3(256), dim3(128), 0, stream,
                       x, sol, W1, b1, W2, b2, W3, b3, y, T);
}